// Round 9
// baseline (257.929 us; speedup 1.0000x reference)
//
#include <hip/hip_runtime.h>

#define NB 32
#define NC 3
#define NK 64
#define KS 7
#define IH 224
#define IW 224
#define OH 218
#define OW 218
#define OHW (OH * OW)
#define ROWS 8        // output rows per block (per-row double-buffered)

typedef float  f32x2  __attribute__((ext_vector_type(2)));
typedef float  f32x4  __attribute__((ext_vector_type(4)));
typedef float  f32x16 __attribute__((ext_vector_type(16)));
typedef short  s16x8  __attribute__((ext_vector_type(8)));
typedef unsigned long long u64;

static __device__ __forceinline__ unsigned short f2bf(float f) {
  unsigned int u = __float_as_uint(f);
  u += 0x7FFFu + ((u >> 16) & 1u);
  return (unsigned short)(u >> 16);
}

// XOR block-swizzle on a 32-u16 (64 B) row: 16B-block ^= (row>>1)&3. (XT only)
static __device__ __forceinline__ int swz(int r, int ci) {
  return (((ci >> 3) ^ ((r >> 1) & 3)) << 3) | (ci & 7);
}

// ---------------- prep kernels ----------------

// fused: x -> bf16, s = sum_c x^2 (LDS), row box -> t[b][h][ow]
__global__ void k_prep_xrow(const float* __restrict__ x, unsigned short* __restrict__ xb,
                            float* __restrict__ t) {
  __shared__ float s_lds[IW];
  const int n  = blockIdx.x;          // NB*IH
  const int b  = n / IH;
  const int h  = n - b * IH;
  const int px = threadIdx.x;
  if (px < IW) {
    float acc = 0.f;
#pragma unroll
    for (int c = 0; c < NC; ++c) {
      size_t idx = ((size_t)(b * NC + c) * IH + h) * IW + px;
      float v = x[idx];
      xb[idx] = f2bf(v);
      acc += v * v;
    }
    s_lds[px] = acc;
  }
  __syncthreads();
  if (px < OW) {
    float acc = 0.f;
#pragma unroll
    for (int j = 0; j < KS; ++j) acc += s_lds[px + j];
    t[(size_t)(b * IH + h) * OW + px] = acc;
  }
}

// col box: x2[b][oh][ow] = sum_{i<7} t[b][oh+i][ow]
__global__ void k_colbox(const float* __restrict__ t, float* __restrict__ x2) {
  int n = blockIdx.x * 256 + threadIdx.x;            // NB*OH*OW
  if (n >= NB * OH * OW) return;
  int b = n / (OH * OW);
  int r = n - b * (OH * OW);
  int oh = r / OW;
  int ow = r - oh * OW;
  const float* col = t + (size_t)(b * IH + oh) * OW + ow;
  float acc = 0.f;
#pragma unroll
  for (int i = 0; i < KS; ++i) acc += col[i * OW];
  x2[n] = acc;
}

// WTg LINEAR: WTg[(j*64+k)*32 + ci] = bf16(memes[k][c][i][j]), ci=c*7+i (<21), 0 above.
// (A is consumed from registers now — no LDS swizzle needed.)
__global__ void k_prep_w(const float* __restrict__ memes, unsigned short* __restrict__ WTg,
                         float* __restrict__ m2inv) {
  __shared__ float red[3];
  const int k = blockIdx.x, t = threadIdx.x;
  float v = 0.f;
  if (t < 147) v = memes[k * 147 + t];
  float s = v * v;
#pragma unroll
  for (int sh = 32; sh > 0; sh >>= 1) s += __shfl_down(s, sh, 64);
  if ((t & 63) == 0) red[t >> 6] = s;
  __syncthreads();
  if (t == 0) m2inv[k] = 1.0f / (red[0] + red[1] + red[2]);
  if (t < 147) {
    int c = t / 49, rem = t - 49 * c, i = rem / 7, j = rem - 7 * i;
    WTg[(j * NK + k) * 32 + (c * 7 + i)] = f2bf(v);
  }
  for (int idx = t; idx < 7 * 11; idx += 192) {
    int j = idx / 11, ci = 21 + (idx - 11 * j);
    WTg[(j * NK + k) * 32 + ci] = 0;
  }
}

// ---------------- per-row staging (issue-early / write-late) ----------------
// One row = 21 ci x 18 tq (u64 = 4 px) = 378 slots over 256 threads * 2.
static __device__ __forceinline__ void xt_issue(u64 v[2],
    const unsigned short* __restrict__ xb, int b, int oh, int ow0, int tid) {
#pragma unroll
  for (int m = 0; m < 2; ++m) {
    int idx = tid + 256 * m;
    u64 val = 0;
    if (idx < 378) {
      int tq = idx % 18;
      int ci = idx / 18;
      int c  = ci / 7;
      int i  = ci - 7 * c;
      // unguarded: overreads stay inside ws (finite bits), feed only masked lanes
      val = *(const u64*)&xb[((size_t)(b * NC + c) * IH + oh + i) * IW + ow0 + 4 * tq];
    }
    v[m] = val;
  }
}

static __device__ __forceinline__ void xt_write(unsigned short* __restrict__ XT,
    const u64 v[2], int tid) {
#pragma unroll
  for (int m = 0; m < 2; ++m) {
    int idx = tid + 256 * m;
    if (idx < 378) {
      int tq = idx % 18;
      int ci = idx / 18;
#pragma unroll
      for (int e = 0; e < 4; ++e) {
        int t = 4 * tq + e;
        XT[t * 32 + swz(t, ci)] = (unsigned short)(v[m] >> (16 * e));
      }
    }
  }
}

// ---------------- main MFMA kernel (32x32x16, A in registers, OT epilogue) ----
// Block: 256 thr (4 waves), 4 blocks/CU. Wave = (k-half, px-half) quadrant.
// Epilogue: acc -> OT (LDS transpose) -> 256B-contiguous segment stores.
__global__ __launch_bounds__(256, 4) void k_main(
    const unsigned short* __restrict__ xb, const float* __restrict__ x2g,
    const unsigned short* __restrict__ WTg, const float* __restrict__ m2inv,
    float* __restrict__ out) {
  __shared__ __align__(16) unsigned short XTl[2][72 * 32];  //  9216 B
  __shared__ __align__(16) float OT[NK][64];                // 16384 B
  __shared__ float m2l[NK];                                 //   256 B

  const int tid  = threadIdx.x;
  const int lane = tid & 63;
  const int w    = tid >> 6;
  const int l31  = lane & 31;
  const int hsel = lane >> 5;       // 0/1: ci-slice / D-subrow group
  const int kh   = w >> 1;          // k-half (0: k 0..31, 1: k 32..63)
  const int ph   = w & 1;           // px-half (0: px 0..31, 1: 32..63)

  // XCD-chunked bijective swizzle: 3584 blocks = 8 XCD x 448.
  const int wg  = blockIdx.x;
  const int sw  = (wg & 7) * 448 + (wg >> 3);
  const int ow0 = (sw & 3) * 64;
  const int ohb = ((sw >> 2) % 28) * ROWS;
  const int b   = sw / 112;

  // A fragments into 56 VGPRs (L2-hot linear WTg); row = j*64 + kh*32 + l31
  s16x8 Af[KS][2];
  {
    const unsigned short* ap = WTg + ((size_t)(kh * 32 + l31) * 32 + hsel * 8);
#pragma unroll
    for (int j = 0; j < KS; ++j) {
      Af[j][0] = *(const s16x8*)&ap[j * (NK * 32)];        // ci 0..15 slice
      Af[j][1] = *(const s16x8*)&ap[j * (NK * 32) + 16];   // ci 16..31 slice
    }
  }
  if (tid < NK) m2l[tid] = m2inv[tid];

  // zero pad lanes ci=21..31 in BOTH XT buffers (MFMA reads them; 0*NaN=NaN!)
  for (int idx = tid; idx < 2 * 72; idx += 256) {
    int bb = idx / 72, t = idx - 72 * bb;
    unsigned short* row = &XTl[bb][t * 32];
    const int m = (t >> 1) & 3;
    *(uint4*)&row[(3 ^ m) << 3] = (uint4){0, 0, 0, 0};   // ci 24..31
    const int b2 = (2 ^ m) << 3;                          // ci 21..23
    row[b2 + 5] = 0; row[b2 + 6] = 0; row[b2 + 7] = 0;
  }

  u64 s0[2];
  xt_issue(s0, xb, b, ohb, ow0, tid);
  xt_write(&XTl[0][0], s0, tid);
  asm volatile("s_waitcnt lgkmcnt(0)" ::: "memory");
  __builtin_amdgcn_s_barrier();

  const int tB   = ph * 32 + l31;   // this lane's px (== D col + ph*32)
  const int g16  = tid >> 4;        // 0..15: epilogue segment group
  const int l16  = tid & 15;        // position within segment (4 floats)
  const bool edge = (ow0 + 64 > OW);            // last ow tile only
  const float* x2b = x2g + (size_t)b * OH * OW + ow0 + l16 * 4;
  float* outb = out + (size_t)b * NK * OHW + ow0 + l16 * 4;

#pragma unroll 1
  for (int r = 0; r < ROWS; ++r) {
    const int oh = ohb + r;
    const bool more = (r + 1 < ROWS);

    u64 sn[2];
    if (more) xt_issue(sn, xb, b, oh + 1, ow0, tid);   // loads fly over MFMAs

    const unsigned short* XT = &XTl[r & 1][0];
    f32x16 accA = {0.f,0.f,0.f,0.f,0.f,0.f,0.f,0.f,0.f,0.f,0.f,0.f,0.f,0.f,0.f,0.f};
    f32x16 accB = accA;

#pragma unroll
    for (int j = 0; j < KS; ++j) {
      const int t = tB + j;
      const unsigned short* br = XT + t * 32;
      const int swzB = (t >> 1) & 3;
      s16x8 bA = *(const s16x8*)&br[(hsel ^ swzB) << 3];
      s16x8 bB = *(const s16x8*)&br[((2 + hsel) ^ swzB) << 3];
      accA = __builtin_amdgcn_mfma_f32_32x32x16_bf16(Af[j][0], bA, accA, 0, 0, 0);
      accB = __builtin_amdgcn_mfma_f32_32x32x16_bf16(Af[j][1], bB, accB, 0, 0, 0);
    }
    const f32x16 acc = accA + accB;

    if (oh < OH) {                    // block-uniform
      // transpose: D row (reg) -> k; D col (l31, +ph*32) -> px. 2-way banks (free).
#pragma unroll
      for (int reg = 0; reg < 16; ++reg)
        OT[kh * 32 + 4 * hsel + 8 * (reg >> 2) + (reg & 3)][tB] = acc[reg];
      asm volatile("s_waitcnt lgkmcnt(0)" ::: "memory");
      __builtin_amdgcn_s_barrier();

      // each 16-lane group stores one full (k,oh) 256B segment, contiguous.
      const float* x2p = x2b + (size_t)oh * OW;
      f32x2 x2lo = *(const f32x2*)&x2p[0];     // 8B-aligned always
      f32x2 x2hi = *(const f32x2*)&x2p[2];
#pragma unroll
      for (int i = 0; i < 4; ++i) {
        const int k = g16 + 16 * i;
        f32x4 v = *(const f32x4*)&OT[k][l16 * 4];
        const float ms = m2l[k];
        f32x2 rlo, rhi;
        rlo[0] = (x2lo[0] - 2.0f * v[0]) * ms + 1.0f;
        rlo[1] = (x2lo[1] - 2.0f * v[1]) * ms + 1.0f;
        rhi[0] = (x2hi[0] - 2.0f * v[2]) * ms + 1.0f;
        rhi[1] = (x2hi[1] - 2.0f * v[3]) * ms + 1.0f;
        float* op = outb + (size_t)k * OHW + (size_t)oh * OW;
        if (!edge) {
          *(f32x2*)&op[0] = rlo;               // 8B-aligned (all strides % 8 == 0)
          *(f32x2*)&op[2] = rhi;
        } else {
          const int base = l16 * 4, lim = OW - ow0;   // 26
          if (base     < lim) op[0] = rlo[0];
          if (base + 1 < lim) op[1] = rlo[1];
          if (base + 2 < lim) op[2] = rhi[0];
          if (base + 3 < lim) op[3] = rhi[1];
        }
      }
      // OT reads drained before next row's OT writes by the end-of-row barrier.
    }

    if (more) {
      xt_write(&XTl[(r + 1) & 1][0], sn, tid);  // other-parity buffer: no hazard
      asm volatile("s_waitcnt lgkmcnt(0)" ::: "memory");
      __builtin_amdgcn_s_barrier();             // orders OT reads + XT writes
    }
  }
}

// ---------------- launch ----------------
extern "C" void kernel_launch(void* const* d_in, const int* in_sizes, int n_in,
                              void* d_out, int out_size, void* d_ws, size_t ws_size,
                              hipStream_t stream) {
  const float* x     = (const float*)d_in[0];   // [32,3,224,224]
  const float* memes = (const float*)d_in[1];   // [64,3,7,7]
  float* out = (float*)d_out;                   // [32,64,218,218]

  char* ws = (char*)d_ws;
  unsigned short* xb  = (unsigned short*)(ws);                 // 9,633,792 B
  float* t            = (float*)(ws + 9633792);                // 6,250,496 B
  float* x2           = (float*)(ws + 15884288);               // 6,083,072 B
  // 512 B slack after x2: epilogue x2 tail reads (masked lanes) stay in-ws/finite
  unsigned short* WTg = (unsigned short*)(ws + 21967872);      // 28,672 B
  float* m2inv        = (float*)(ws + 21996544);               // 256 B

  (void)in_sizes; (void)n_in; (void)out_size; (void)ws_size;

  k_prep_xrow<<<NB * IH, 256, 0, stream>>>(x, xb, t);
  k_colbox<<<(NB * OH * OW + 255) / 256, 256, 0, stream>>>(t, x2);
  k_prep_w<<<NK, 192, 0, stream>>>(memes, WTg, m2inv);

  // 3584 blocks = 4 ow-tiles x 28 oh-blocks x 32 b, flattened for XCD swizzle
  k_main<<<4 * 28 * NB, 256, 0, stream>>>(xb, x2, WTg, m2inv, out);
}

// Round 10
// 160.328 us; speedup vs baseline: 1.6088x; 1.6088x over previous
//
#include <hip/hip_runtime.h>

#define NB 32
#define NC 3
#define NK 64
#define KS 7
#define IH 224
#define IW 224
#define OH 218
#define OW 218
#define OHW (OH * OW)
#define ROWS 8        // output rows per block (per-row double-buffered)

typedef float  f32x4  __attribute__((ext_vector_type(4)));
typedef float  f32x16 __attribute__((ext_vector_type(16)));
typedef short  s16x8  __attribute__((ext_vector_type(8)));
typedef unsigned long long u64;

static __device__ __forceinline__ unsigned short f2bf(float f) {
  unsigned int u = __float_as_uint(f);
  u += 0x7FFFu + ((u >> 16) & 1u);
  return (unsigned short)(u >> 16);
}

// XOR block-swizzle on a 32-u16 (64 B) row: 16B-block ^= (row>>1)&3.
static __device__ __forceinline__ int swz(int r, int ci) {
  return (((ci >> 3) ^ ((r >> 1) & 3)) << 3) | (ci & 7);
}

// ---------------- prep kernels ----------------

// fused: x -> bf16, s = sum_c x^2 (LDS), row box -> t[b][h][ow]
__global__ void k_prep_xrow(const float* __restrict__ x, unsigned short* __restrict__ xb,
                            float* __restrict__ t) {
  __shared__ float s_lds[IW];
  const int n  = blockIdx.x;          // NB*IH
  const int b  = n / IH;
  const int h  = n - b * IH;
  const int px = threadIdx.x;
  if (px < IW) {
    float acc = 0.f;
#pragma unroll
    for (int c = 0; c < NC; ++c) {
      size_t idx = ((size_t)(b * NC + c) * IH + h) * IW + px;
      float v = x[idx];
      xb[idx] = f2bf(v);
      acc += v * v;
    }
    s_lds[px] = acc;
  }
  __syncthreads();
  if (px < OW) {
    float acc = 0.f;
#pragma unroll
    for (int j = 0; j < KS; ++j) acc += s_lds[px + j];
    t[(size_t)(b * IH + h) * OW + px] = acc;
  }
}

// WTg[row=j*64+k][ci'(swizzled, 32)] = bf16(memes[k][c][i][j]); zeros at ci>=21.
__global__ void k_prep_w(const float* __restrict__ memes, unsigned short* __restrict__ WTg,
                         float* __restrict__ m2inv) {
  __shared__ float red[3];
  const int k = blockIdx.x, t = threadIdx.x;
  float v = 0.f;
  if (t < 147) v = memes[k * 147 + t];
  float s = v * v;
#pragma unroll
  for (int sh = 32; sh > 0; sh >>= 1) s += __shfl_down(s, sh, 64);
  if ((t & 63) == 0) red[t >> 6] = s;
  __syncthreads();
  if (t == 0) m2inv[k] = 1.0f / (red[0] + red[1] + red[2]);
  if (t < 147) {
    int c = t / 49, rem = t - 49 * c, i = rem / 7, j = rem - 7 * i;
    int row = j * NK + k;
    WTg[row * 32 + swz(row, c * 7 + i)] = f2bf(v);
  }
  for (int idx = t; idx < 7 * 11; idx += 192) {
    int j = idx / 11, ci = 21 + (idx - 11 * j);
    int row = j * NK + k;
    WTg[row * 32 + swz(row, ci)] = 0;
  }
}

// ---------------- per-row staging (issue-early / write-late) ----------------
// One row = 21 ci x 18 tq (u64 = 4 px) = 378 slots over 256 threads * 2.
static __device__ __forceinline__ void xt_issue(u64 v[2],
    const unsigned short* __restrict__ xb, int b, int oh, int ow0, int tid) {
#pragma unroll
  for (int m = 0; m < 2; ++m) {
    int idx = tid + 256 * m;
    u64 val = 0;
    if (idx < 378) {
      int tq = idx % 18;
      int ci = idx / 18;
      int c  = ci / 7;
      int i  = ci - 7 * c;
      // unguarded: overreads stay inside ws (finite bits), feed only masked lanes
      val = *(const u64*)&xb[((size_t)(b * NC + c) * IH + oh + i) * IW + ow0 + 4 * tq];
    }
    v[m] = val;
  }
}

static __device__ __forceinline__ void xt_write(unsigned short* __restrict__ XT,
    const u64 v[2], int tid) {
#pragma unroll
  for (int m = 0; m < 2; ++m) {
    int idx = tid + 256 * m;
    if (idx < 378) {
      int tq = idx % 18;
      int ci = idx / 18;
#pragma unroll
      for (int e = 0; e < 4; ++e) {
        int t = 4 * tq + e;
        XT[t * 32 + swz(t, ci)] = (unsigned short)(v[m] >> (16 * e));
      }
    }
  }
}

// One row iteration: issue next-row loads, STORE the PREVIOUS row's buffered
// outputs (drain overlaps this row's MFMAs), compute this row into the other
// output set. OVST/OVCP are distinct named registers -> fully static.
#define ROW_BODY(R, OVST, OHST, OVCP, OHCP)                                      \
  do {                                                                           \
    const int oh_ = ohb + (R);                                                   \
    const bool more_ = ((R) + 1 < ROWS);                                         \
    u64 sn_[2];                                                                  \
    if (more_) xt_issue(sn_, xb, b, oh_ + 1, ow0, tid);                          \
    if ((OHST) >= 0) {   /* deferred store of previous row (exec-masked) */      \
      float* ob_ = out + ((size_t)(b * NK + kh * 32) * OH + (OHST)) * OW + ow;   \
      _Pragma("unroll")                                                          \
      for (int reg = 0; reg < 16; ++reg) {                                       \
        const int kk = (reg & 3) + 8 * (reg >> 2) + 4 * hsel;                    \
        ob_[(size_t)kk * OHW] = (OVST)[reg];                                     \
      }                                                                          \
    }                                                                            \
    const bool ok_ = (ow < OW) && (oh_ < OH);                                    \
    float x2v_ = 0.f;                                                            \
    if (ok_) {   /* colbox fused: 7 L2-hot loads, overlap the MFMAs below */     \
      const float* tp_ = tg + ((size_t)b * IH + oh_) * OW + ow;                  \
      _Pragma("unroll")                                                          \
      for (int i = 0; i < KS; ++i) x2v_ += tp_[i * OW];                          \
    }                                                                            \
    const unsigned short* XT_ = &XTl[(R) & 1][0];                                \
    f32x16 accA_ = {0.f,0.f,0.f,0.f,0.f,0.f,0.f,0.f,                             \
                    0.f,0.f,0.f,0.f,0.f,0.f,0.f,0.f};                            \
    f32x16 accB_ = accA_;                                                        \
    _Pragma("unroll")                                                            \
    for (int j = 0; j < KS; ++j) {                                               \
      const unsigned short* ar_ = WTl + (j * 64 + kh * 32 + l31) * 32;           \
      s16x8 aA_ = *(const s16x8*)&ar_[(hsel ^ swzA) << 3];                       \
      s16x8 aB_ = *(const s16x8*)&ar_[((2 + hsel) ^ swzA) << 3];                 \
      const int t_ = tB + j;                                                     \
      const unsigned short* br_ = XT_ + t_ * 32;                                 \
      const int swzB_ = (t_ >> 1) & 3;                                           \
      s16x8 bA_ = *(const s16x8*)&br_[(hsel ^ swzB_) << 3];                      \
      s16x8 bB_ = *(const s16x8*)&br_[((2 + hsel) ^ swzB_) << 3];                \
      accA_ = __builtin_amdgcn_mfma_f32_32x32x16_bf16(aA_, bA_, accA_, 0, 0, 0); \
      accB_ = __builtin_amdgcn_mfma_f32_32x32x16_bf16(aB_, bB_, accB_, 0, 0, 0); \
    }                                                                            \
    const f32x16 acc_ = accA_ + accB_;                                           \
    _Pragma("unroll")                                                            \
    for (int reg = 0; reg < 16; ++reg)                                           \
      (OVCP)[reg] = (x2v_ - 2.0f * acc_[reg]) * m2r[reg >> 2][reg & 3] + 1.0f;   \
    (OHCP) = ok_ ? oh_ : -1;                                                     \
    if (more_) {                                                                 \
      xt_write(&XTl[((R) + 1) & 1][0], sn_, tid);                                \
      asm volatile("s_waitcnt lgkmcnt(0)" ::: "memory");                         \
      __builtin_amdgcn_s_barrier();                                              \
    }                                                                            \
  } while (0)

// ---------------- main MFMA kernel (32x32x16, deferred-store pipeline) -------
__global__ __launch_bounds__(256, 4) void k_main(
    const unsigned short* __restrict__ xb, const float* __restrict__ tg,
    const unsigned short* __restrict__ WTg, const float* __restrict__ m2inv,
    float* __restrict__ out) {
  __shared__ __align__(16) unsigned short WTl[KS * NK * 32];   // 28672 B
  __shared__ __align__(16) unsigned short XTl[2][72 * 32];     // 9216 B

  const int tid  = threadIdx.x;
  const int w    = tid >> 6;
  const int lane = tid & 63;
  const int l31  = lane & 31;
  const int hsel = lane >> 5;       // 0/1: k-subrow group
  const int kh   = w >> 1;          // k-half (0: k 0..31, 1: k 32..63)
  const int ph   = w & 1;           // px-half (0: px 0..31, 1: 32..63)

  // XCD-chunked bijective swizzle: 3584 blocks = 8 XCD x 448.
  const int wg  = blockIdx.x;
  const int sw  = (wg & 7) * 448 + (wg >> 3);
  const int ow0 = (sw & 3) * 64;
  const int ohb = ((sw >> 2) % 28) * ROWS;
  const int b   = sw / 112;

  // WT: linear async copy global->LDS (28 x 1024 B)
  for (int ch = w; ch < 28; ch += 4) {
    const unsigned short* g = WTg + ch * 512 + lane * 8;
    unsigned short* l = WTl + ch * 512;
    __builtin_amdgcn_global_load_lds((const __attribute__((address_space(1))) void*)g,
                                     (__attribute__((address_space(3))) void*)l, 16, 0, 0);
  }

  // m2 in 16 regs: k = kh*32 + 4*hsel + 8*g + (reg&3)
  f32x4 m2r[4];
  {
    const float* mp = m2inv + kh * 32 + 4 * hsel;
#pragma unroll
    for (int g = 0; g < 4; ++g) m2r[g] = *(const f32x4*)&mp[8 * g];
  }

  // zero pad lanes ci=21..31 in BOTH buffers (MFMA reads them; 0*NaN=NaN!)
  for (int idx = tid; idx < 2 * 72; idx += 256) {
    int bb = idx / 72, t = idx - 72 * bb;
    unsigned short* row = &XTl[bb][t * 32];
    const int m = (t >> 1) & 3;
    *(uint4*)&row[(3 ^ m) << 3] = (uint4){0, 0, 0, 0};   // ci 24..31
    const int b2 = (2 ^ m) << 3;                          // ci 21..23
    row[b2 + 5] = 0; row[b2 + 6] = 0; row[b2 + 7] = 0;
  }

  u64 s0[2];
  xt_issue(s0, xb, b, ohb, ow0, tid);
  xt_write(&XTl[0][0], s0, tid);
  asm volatile("s_waitcnt vmcnt(0) lgkmcnt(0)" ::: "memory");  // WT lds + XT writes
  __builtin_amdgcn_s_barrier();

  const int swzA = (l31 >> 1) & 3;  // A row = j*64 + kh*32 + l31 -> (row>>1)&3
  const int tB   = ph * 32 + l31;   // this lane's px within the 64-tile
  const int ow   = ow0 + tB;

  f32x16 ovA, ovB;
  int ohA = -1, ohB = -1;

  ROW_BODY(0, ovB, ohB, ovA, ohA);            // compute row 0 -> A (no store yet)
#pragma unroll 1
  for (int rp = 0; rp < 3; ++rp) {
    ROW_BODY(2 * rp + 1, ovA, ohA, ovB, ohB); // store row 2rp   (A), compute -> B
    ROW_BODY(2 * rp + 2, ovB, ohB, ovA, ohA); // store row 2rp+1 (B), compute -> A
  }
  ROW_BODY(7, ovA, ohA, ovB, ohB);            // store row 6 (A), compute row 7 -> B

  if (ohB >= 0) {                             // final store: row 7
    float* ob = out + ((size_t)(b * NK + kh * 32) * OH + ohB) * OW + ow;
#pragma unroll
    for (int reg = 0; reg < 16; ++reg) {
      const int kk = (reg & 3) + 8 * (reg >> 2) + 4 * hsel;
      ob[(size_t)kk * OHW] = ovB[reg];
    }
  }
}

// ---------------- launch ----------------
extern "C" void kernel_launch(void* const* d_in, const int* in_sizes, int n_in,
                              void* d_out, int out_size, void* d_ws, size_t ws_size,
                              hipStream_t stream) {
  const float* x     = (const float*)d_in[0];   // [32,3,224,224]
  const float* memes = (const float*)d_in[1];   // [64,3,7,7]
  float* out = (float*)d_out;                   // [32,64,218,218]

  char* ws = (char*)d_ws;
  unsigned short* xb  = (unsigned short*)(ws);                 // 9,633,792 B
  float* t            = (float*)(ws + 9633792);                // 6,250,496 B
  unsigned short* WTg = (unsigned short*)(ws + 15884288);      // 28,672 B
  float* m2inv        = (float*)(ws + 15912960);               // 256 B

  (void)in_sizes; (void)n_in; (void)out_size; (void)ws_size;

  k_prep_xrow<<<NB * IH, 256, 0, stream>>>(x, xb, t);
  k_prep_w<<<NK, 192, 0, stream>>>(memes, WTg, m2inv);

  // 3584 blocks = 4 ow-tiles x 28 oh-blocks x 32 b, flattened for XCD swizzle
  k_main<<<4 * 28 * NB, 256, 0, stream>>>(xb, t, WTg, m2inv, out);
}